// Round 3
// baseline (535.628 us; speedup 1.0000x reference)
//
#include <hip/hip_runtime.h>
#include <hip/hip_bf16.h>

typedef unsigned short u16;
typedef unsigned int u32;
typedef __attribute__((ext_vector_type(8))) short short8;
typedef __attribute__((ext_vector_type(4))) float f32x4;

#define NB 64
#define NS 2048
#define ND 512
#define NU 256
#define CH 32              // rows per chunk
#define CPB (NS / CH)      // 64 chunks per batch
#define CHBLK 8            // chunks per persistent block
#define GRID (NB * CPB / CHBLK)   // 512 blocks = exactly 2 per CU
// A row stride in u16: 512 + 8 pad -> 260 dwords/row (4 mod 32: afr b128 reads uniform 8-way phase = conflict-free, verified empirically r0-r2)
#define ASTR 520

__device__ __forceinline__ u16 f2b(float f) {
    u32 x = __float_as_uint(f);
    u32 r = (x + 0x7FFFu + ((x >> 16) & 1u)) >> 16;   // RNE
    return (u16)r;
}
__device__ __forceinline__ u32 pk2(float lo, float hi) {
    __hip_bfloat162 h = __float22bfloat162_rn(float2{lo, hi});
    return *(u32*)&h;
}
__device__ __forceinline__ float fast_tanh(float x) {
    float e = __expf(2.0f * x);
    return 1.0f - 2.0f / (e + 1.0f);
}
// Raw barrier: does NOT drain vmcnt -> global prefetch loads stay in flight
// across it (the whole point; __syncthreads would emit s_waitcnt vmcnt(0)).
// lgkmcnt(0) publishes this wave's ds_writes before the barrier.
__device__ __forceinline__ void wg_barrier() {
    asm volatile("s_waitcnt lgkmcnt(0)" ::: "memory");
    __builtin_amdgcn_s_barrier();
}

// ---------------------------------------------------------------------------
// Kernel 1 (PREP): blocks 0..63  -> cb[b][u] = q[b]·W2[:,u] + b1[u] + b2[u]
//                  blocks 64..71 -> repack W1 into MFMA-fragment order:
//   W1Tf[frag f][lane][j],  f = kc*32 + wn*8 + kh*4 + cbk
// ---------------------------------------------------------------------------
__global__ __launch_bounds__(256) void prep_kernel(
    const float* __restrict__ q, const float* __restrict__ W2,
    const float* __restrict__ b1, const float* __restrict__ b2,
    const float* __restrict__ W1,
    float* __restrict__ cb, u16* __restrict__ W1Tf)
{
    const int tid = threadIdx.x;
    if (blockIdx.x < 64) {
        int b = blockIdx.x, u = tid;
        __shared__ float qs[ND];
        qs[u]       = q[b * ND + u];
        qs[u + 256] = q[b * ND + u + 256];
        __syncthreads();
        float acc = 0.f;
#pragma unroll 8
        for (int d = 0; d < ND; d++)
            acc += qs[d] * W2[d * NU + u];
        cb[b * NU + u] = acc + b1[u] + b2[u];
    } else {
        int blk = blockIdx.x - 64;          // 0..7
#pragma unroll
        for (int it = 0; it < 8; it++) {
            int id   = blk * 2048 + it * 256 + tid;   // fragment-lane id
            int f    = id >> 6, lane = id & 63;
            int cbk  = f & 3, kh = (f >> 2) & 1, wn = (f >> 3) & 3, kc = f >> 5;
            int m16  = lane & 15, quad = lane >> 4;
            int u    = wn * 64 + cbk * 16 + m16;
            int kb   = kc * 64 + kh * 32 + quad * 8;
            u16 tmp[8];
#pragma unroll
            for (int j = 0; j < 8; j++)
                tmp[j] = f2b(W1[(kb + j) * NU + u]);
            *(uint4*)&W1Tf[(size_t)id * 8] = *(uint4*)tmp;
        }
    }
}

// ---------------------------------------------------------------------------
// Kernel 2 (FUSED, persistent): 512 blocks (2/CU), each owns 8 consecutive
// 32-row chunks of one batch. Double-buffered A in LDS; per chunk:
//   1. issue next chunk's global loads (issue-early)
//   2. MFMA sweep on current buffer (B frags double-buffered from L2)
//   3. score + per-wave slots -> barrier
//   4. wave0 chunk softmax -> barrier
//   5. phase3 weighted values sum -> ctxp store
//   6. cvt + ds_write next chunk into other buffer (write-late) -> barrier
// Raw barriers keep the HBM prefetch in flight across all of 3/4/6 -> the
// memory pipe sees continuous demand instead of 14% duty cycle.
// LDS 69.3 KB -> 2 blocks/CU (8 waves).
// ---------------------------------------------------------------------------
__global__ __launch_bounds__(256, 2) void fused_kernel(
    const float* __restrict__ values, // [64][2048][512] fp32
    const u16* __restrict__ W1Tf,     // [256 frags][64 lanes][8] bf16
    const float* __restrict__ cb,     // [64][256]
    const float* __restrict__ V,      // [256]
    float* __restrict__ ctxp,         // [4096][512] chunk context partials
    float2* __restrict__ meta)        // [4096] (m_loc, l_loc)
{
    const int tid  = threadIdx.x;
    const int lane = tid & 63;
    const int wn   = tid >> 6;        // 0..3 (N dim)
    const int m16  = lane & 15;
    const int quad = lane >> 4;

    const int chunk0 = blockIdx.x * CHBLK;    // 8 consecutive chunks, same batch
    const int b      = chunk0 >> 6;

    __shared__ u16 Abuf[2][CH][ASTR];         // 66.6 KB double buffer
    __shared__ float cbs[NU];
    __shared__ float Vs[NU];
    __shared__ float rsum4[4][CH];            // per-wave score partials
    __shared__ float wsm[CH];

    cbs[tid] = cb[b * NU + tid];
    Vs[tid]  = V[tid];

    // staging geometry: 8 threads/row, thread covers 4x16 f32 at stride 128
    const int r  = tid >> 3;                  // 0..31
    const int k8 = tid & 7;                   // 0..7
    const float* abase = values + ((size_t)chunk0 * CH + r) * ND + k8 * 16;

    const u16* pB = W1Tf + wn * 4096 + lane * 8;

    // ---- prologue: stage chunk 0 into Abuf[0] ----
    {
        float4 av[4][4];
#pragma unroll
        for (int j = 0; j < 4; j++)
#pragma unroll
            for (int qq = 0; qq < 4; qq++)
                av[j][qq] = ((const float4*)(abase + j * 128))[qq];
#pragma unroll
        for (int j = 0; j < 4; j++) {
            uint4 q0, q1;
            q0.x = pk2(av[j][0].x, av[j][0].y); q0.y = pk2(av[j][0].z, av[j][0].w);
            q0.z = pk2(av[j][1].x, av[j][1].y); q0.w = pk2(av[j][1].z, av[j][1].w);
            q1.x = pk2(av[j][2].x, av[j][2].y); q1.y = pk2(av[j][2].z, av[j][2].w);
            q1.z = pk2(av[j][3].x, av[j][3].y); q1.w = pk2(av[j][3].z, av[j][3].w);
            *(uint4*)&Abuf[0][r][k8 * 16 + j * 128]     = q0;
            *(uint4*)&Abuf[0][r][k8 * 16 + j * 128 + 8] = q1;
        }
    }
    wg_barrier();

    for (int c = 0; c < CHBLK; c++) {
        const int p = c & 1;
        const int chunk = chunk0 + c;

        // ---- 1. issue next chunk's A loads (consumed in step 6) ----
        float4 av[4][4];
        if (c < CHBLK - 1) {
            const float* src = abase + (size_t)(c + 1) * CH * ND;
#pragma unroll
            for (int j = 0; j < 4; j++)
#pragma unroll
                for (int qq = 0; qq < 4; qq++)
                    av[j][qq] = ((const float4*)(src + j * 128))[qq];
        }

        // ---- 2. MFMA sweep over Abuf[p], B double-buffered from L2 ----
        f32x4 acc[2][4] = {};
        short8 bfr[2][8];
#pragma unroll
        for (int f = 0; f < 8; f++)
            bfr[0][f] = *(const short8*)(pB + f * 512);
#pragma unroll
        for (int kc = 0; kc < 8; kc++) {
            const int cur = kc & 1;
            if (kc < 7) {
#pragma unroll
                for (int f = 0; f < 8; f++)
                    bfr[cur ^ 1][f] = *(const short8*)(pB + (kc + 1) * 16384 + f * 512);
            }
            short8 afr[2][2];
#pragma unroll
            for (int kh = 0; kh < 2; kh++)
#pragma unroll
                for (int rb = 0; rb < 2; rb++)
                    afr[kh][rb] = *(const short8*)&Abuf[p][rb * 16 + m16][kc * 64 + kh * 32 + quad * 8];
#pragma unroll
            for (int kh = 0; kh < 2; kh++)
#pragma unroll
                for (int rb = 0; rb < 2; rb++)
#pragma unroll
                    for (int cbk = 0; cbk < 4; cbk++)
                        acc[rb][cbk] = __builtin_amdgcn_mfma_f32_16x16x32_bf16(
                            afr[kh][rb], bfr[cur][kh * 4 + cbk], acc[rb][cbk], 0, 0, 0);
        }

        // ---- 3. scores + per-wave slots (no atomics) ----
        {
            float cbv[4], vv[4];
#pragma unroll
            for (int cbk = 0; cbk < 4; cbk++) {
                int cc = wn * 64 + cbk * 16 + m16;
                cbv[cbk] = cbs[cc];
                vv[cbk]  = Vs[cc];
            }
#pragma unroll
            for (int rb = 0; rb < 2; rb++) {
#pragma unroll
                for (int i = 0; i < 4; i++) {
                    float s = 0.f;
#pragma unroll
                    for (int cbk = 0; cbk < 4; cbk++)
                        s += fast_tanh(acc[rb][cbk][i] + cbv[cbk]) * vv[cbk];
                    s += __shfl_xor(s, 1, 64);
                    s += __shfl_xor(s, 2, 64);
                    s += __shfl_xor(s, 4, 64);
                    s += __shfl_xor(s, 8, 64);
                    if (m16 == 0)
                        rsum4[wn][rb * 16 + quad * 4 + i] = s;
                }
            }
        }
        wg_barrier();

        // ---- 4. wave0: chunk-local softmax, write wsm + meta ----
        if (tid < CH) {
            float s = rsum4[0][tid] + rsum4[1][tid] + rsum4[2][tid] + rsum4[3][tid];
            float m = s;
            m = fmaxf(m, __shfl_xor(m, 1, 64));
            m = fmaxf(m, __shfl_xor(m, 2, 64));
            m = fmaxf(m, __shfl_xor(m, 4, 64));
            m = fmaxf(m, __shfl_xor(m, 8, 64));
            m = fmaxf(m, __shfl_xor(m, 16, 64));
            float w = __expf(s - m);
            wsm[tid] = w;
            float l = w;
            l += __shfl_xor(l, 1, 64);
            l += __shfl_xor(l, 2, 64);
            l += __shfl_xor(l, 4, 64);
            l += __shfl_xor(l, 8, 64);
            l += __shfl_xor(l, 16, 64);
            if (tid == 0) meta[chunk] = float2{m, l};
        }
        wg_barrier();

        // ---- 5. phase3: ctx_partial[d] = sum_row wsm[row] * A[row][d] ----
        {
            const u32* adw = (const u32*)&Abuf[p][0][0];   // row stride 260 dw
            float a0 = 0.f, a1 = 0.f;
#pragma unroll 8
            for (int rr = 0; rr < CH; rr++) {
                u32 pk = adw[rr * (ASTR / 2) + tid];
                float lo = __uint_as_float(pk << 16);
                float hi = __uint_as_float(pk & 0xFFFF0000u);
                float wt = wsm[rr];
                a0 += wt * lo;
                a1 += wt * hi;
            }
            float2* dst = (float2*)(ctxp + (size_t)chunk * ND + tid * 2);
            *dst = float2{a0, a1};
        }

        // ---- 6. write-late: cvt prefetched A into other buffer ----
        if (c < CHBLK - 1) {
#pragma unroll
            for (int j = 0; j < 4; j++) {
                uint4 q0, q1;
                q0.x = pk2(av[j][0].x, av[j][0].y); q0.y = pk2(av[j][0].z, av[j][0].w);
                q0.z = pk2(av[j][1].x, av[j][1].y); q0.w = pk2(av[j][1].z, av[j][1].w);
                q1.x = pk2(av[j][2].x, av[j][2].y); q1.y = pk2(av[j][2].z, av[j][2].w);
                q1.z = pk2(av[j][3].x, av[j][3].y); q1.w = pk2(av[j][3].z, av[j][3].w);
                *(uint4*)&Abuf[p ^ 1][r][k8 * 16 + j * 128]     = q0;
                *(uint4*)&Abuf[p ^ 1][r][k8 * 16 + j * 128 + 8] = q1;
            }
            wg_barrier();
        }
    }
}

// ---------------------------------------------------------------------------
// Kernel 3: combine chunk partials: out[b][d] = sum_c e^{m_c-M} ctx_c[d] / L
// 64 blocks x 256 thr, reads 8 MB.
// ---------------------------------------------------------------------------
__global__ __launch_bounds__(256) void combine_kernel(
    const float* __restrict__ ctxp, const float2* __restrict__ meta,
    float* __restrict__ out)
{
    int b = blockIdx.x, tid = threadIdx.x;
    __shared__ float wc[CPB];
    __shared__ float Ls;
    if (tid < CPB) {                  // lanes 0..63: parallel max + weighted sum
        float2 mt = meta[b * CPB + tid];
        float m = mt.x;
        m = fmaxf(m, __shfl_xor(m, 1, 64));
        m = fmaxf(m, __shfl_xor(m, 2, 64));
        m = fmaxf(m, __shfl_xor(m, 4, 64));
        m = fmaxf(m, __shfl_xor(m, 8, 64));
        m = fmaxf(m, __shfl_xor(m, 16, 64));
        m = fmaxf(m, __shfl_xor(m, 32, 64));
        float w = __expf(mt.x - m);
        wc[tid] = w;
        float l = w * mt.y;
        l += __shfl_xor(l, 1, 64);
        l += __shfl_xor(l, 2, 64);
        l += __shfl_xor(l, 4, 64);
        l += __shfl_xor(l, 8, 64);
        l += __shfl_xor(l, 16, 64);
        l += __shfl_xor(l, 32, 64);
        if (tid == 0) Ls = l;
    }
    __syncthreads();
    float inv = 1.0f / Ls;
    float s0 = 0.f, s1 = 0.f;
#pragma unroll 4
    for (int c = 0; c < CPB; c++) {
        const float* p = ctxp + ((size_t)b * CPB + c) * ND;
        float w = wc[c];
        s0 += w * p[tid];
        s1 += w * p[tid + 256];
    }
    out[b * ND + tid]       = s0 * inv;
    out[b * ND + tid + 256] = s1 * inv;
}

// ---------------------------------------------------------------------------
extern "C" void kernel_launch(void* const* d_in, const int* in_sizes, int n_in,
                              void* d_out, int out_size, void* d_ws, size_t ws_size,
                              hipStream_t stream)
{
    const float* q      = (const float*)d_in[0];   // [64][512]
    const float* values = (const float*)d_in[1];   // [64][2048][512]
    const float* W1     = (const float*)d_in[2];   // [512][256]
    const float* b1     = (const float*)d_in[3];   // [256]
    const float* W2     = (const float*)d_in[4];   // [512][256]
    const float* b2     = (const float*)d_in[5];   // [256]
    const float* V      = (const float*)d_in[6];   // [256]
    // d_in[7] = bV: uniform score shift -> softmax invariant, unused.

    char* ws = (char*)d_ws;
    float*  cb    = (float*) (ws);                       //  65536 B
    u16*    W1Tf  = (u16*)   (ws + 65536);               // 262144 B
    float*  ctxp  = (float*) (ws + 327680);              // 4096*512*4 = 8 MB
    float2* meta  = (float2*)(ws + 327680 + 8388608);    // 32 KB

    hipLaunchKernelGGL(prep_kernel, dim3(72), dim3(256), 0, stream,
                       q, W2, b1, b2, W1, cb, W1Tf);
    hipLaunchKernelGGL(fused_kernel, dim3(GRID), dim3(256), 0, stream,
                       values, W1Tf, cb, V, ctxp, meta);
    hipLaunchKernelGGL(combine_kernel, dim3(64), dim3(256), 0, stream,
                       ctxp, meta, (float*)d_out);
}